// Round 2
// baseline (210.128 us; speedup 1.0000x reference)
//
#include <hip/hip_runtime.h>
#include <hip/hip_bf16.h>
#include <math.h>

#define BATCH 16384
#define DIM   64
#define KCODE 256
#define NMAT  5

static __device__ __forceinline__ float dot4(float4 a, float4 b) {
    return a.x*b.x + a.y*b.y + a.z*b.z + a.w*b.w;
}
static __device__ __forceinline__ float ss4(float4 a) { return dot4(a, a); }
static __device__ __forceinline__ float4 exp4(float4 v, float s) {
    return make_float4(__expf(v.x*s), __expf(v.y*s), __expf(v.z*s), __expf(v.w*s));
}

// ---------------------------------------------------------------------------
// Kernel 1: fused gather + l2norm(A rows) + l2norm(W rows) + SGEMM
// C[m][b][k] = <A_m[b,:], W_m[k,:]>, A gathered+normalized, W normalized.
// Block tile: 64 rows x 128 cols, full K-dim (D=64) staged. 256 threads,
// thread tile 8 rows x 4 cols (cols strided by 32 for conflict-free LDS reads).
// LDS = 16K(As) + 32K(Ws) + 2K(red) = 50K -> 3 blocks/CU.
// ---------------------------------------------------------------------------
__global__ __launch_bounds__(256) void gemm_code_kernel(
    const float* __restrict__ user_emb,
    const float* __restrict__ id_emb,
    const float* __restrict__ image_emb,
    const float* __restrict__ text_emb,
    const int*  __restrict__ users,
    const int*  __restrict__ items,
    const float* __restrict__ w_feat,
    const float* __restrict__ w_ii,
    float* __restrict__ code)
{
    const int m  = blockIdx.z;
    const int r0 = blockIdx.x * 64;
    const int kh = blockIdx.y;            // 0/1 -> k offset kh*128

    const float* src; const int* idxv; const float* w;
    switch (m) {
        case 0:  src = user_emb;  idxv = users; w = w_feat; break;
        case 1:  src = id_emb;    idxv = items; w = w_feat; break;
        case 2:  src = id_emb;    idxv = items; w = w_ii;   break;
        case 3:  src = image_emb; idxv = items; w = w_ii;   break;
        default: src = text_emb;  idxv = items; w = w_ii;   break;
    }

    __shared__ float As[64][64];     // [d][row]   (transposed A tile)
    __shared__ float Ws[64][128];    // [d][klocal] (transposed W tile)
    __shared__ float redA[4][64];
    __shared__ float redW[2][128];

    const int tid = threadIdx.x;

    // ---- load A rows (gather): thread t -> row (t&63), d-segment (t>>6)*16 ----
    const int ar   = tid & 63;
    const int aseg = tid >> 6;            // wave-uniform
    const int gidx = idxv[r0 + ar];
    const float4* ap = (const float4*)(src + (size_t)gidx * DIM + aseg * 16);
    float4 a0 = ap[0], a1 = ap[1], a2 = ap[2], a3 = ap[3];
    redA[aseg][ar] = ss4(a0) + ss4(a1) + ss4(a2) + ss4(a3);

    // ---- load W rows: thread t -> local k (t&127), d-half (t>>7)*32 ----
    const int wr = tid & 127;
    const int wh = tid >> 7;
    const float4* wp = (const float4*)(w + (size_t)(kh*128 + wr) * DIM + wh * 32);
    float4 w0 = wp[0], w1 = wp[1], w2 = wp[2], w3 = wp[3];
    float4 w4 = wp[4], w5 = wp[5], w6 = wp[6], w7 = wp[7];
    redW[wh][wr] = ss4(w0)+ss4(w1)+ss4(w2)+ss4(w3)+ss4(w4)+ss4(w5)+ss4(w6)+ss4(w7);

    __syncthreads();

    {   // normalize + write A transposed
        float tot = redA[0][ar] + redA[1][ar] + redA[2][ar] + redA[3][ar];
        float inv = 1.0f / fmaxf(sqrtf(tot), 1e-12f);
        float av[16] = {a0.x,a0.y,a0.z,a0.w, a1.x,a1.y,a1.z,a1.w,
                        a2.x,a2.y,a2.z,a2.w, a3.x,a3.y,a3.z,a3.w};
        const int db = aseg * 16;
        #pragma unroll
        for (int j = 0; j < 16; ++j) As[db + j][ar] = av[j] * inv;
    }
    {   // normalize + write W transposed
        float tot = redW[0][wr] + redW[1][wr];
        float inv = 1.0f / fmaxf(sqrtf(tot), 1e-12f);
        float wv[32] = {w0.x,w0.y,w0.z,w0.w, w1.x,w1.y,w1.z,w1.w,
                        w2.x,w2.y,w2.z,w2.w, w3.x,w3.y,w3.z,w3.w,
                        w4.x,w4.y,w4.z,w4.w, w5.x,w5.y,w5.z,w5.w,
                        w6.x,w6.y,w6.z,w6.w, w7.x,w7.y,w7.z,w7.w};
        const int db = wh * 32;
        #pragma unroll
        for (int j = 0; j < 32; ++j) Ws[db + j][wr] = wv[j] * inv;
    }
    __syncthreads();

    // ---- compute: thread (tr = tid>>5 in 0..7, tc = tid&31) ----
    const int tr = tid >> 5;
    const int tc = tid & 31;
    float acc[8][4];
    #pragma unroll
    for (int r = 0; r < 8; ++r)
        #pragma unroll
        for (int c = 0; c < 4; ++c) acc[r][c] = 0.0f;

    #pragma unroll 16
    for (int d = 0; d < 64; ++d) {
        float4 av0 = *(const float4*)&As[d][tr*8];
        float4 av1 = *(const float4*)&As[d][tr*8 + 4];
        float ar8[8] = {av0.x,av0.y,av0.z,av0.w, av1.x,av1.y,av1.z,av1.w};
        float wc[4]  = {Ws[d][tc], Ws[d][tc+32], Ws[d][tc+64], Ws[d][tc+96]};
        #pragma unroll
        for (int r = 0; r < 8; ++r)
            #pragma unroll
            for (int c = 0; c < 4; ++c)
                acc[r][c] = fmaf(ar8[r], wc[c], acc[r][c]);
    }

    float* cbase = code + (size_t)m * BATCH * KCODE + (size_t)r0 * KCODE + kh * 128;
    #pragma unroll
    for (int r = 0; r < 8; ++r) {
        float* crow = cbase + (size_t)(tr*8 + r) * KCODE;
        crow[tc]      = acc[r][0];
        crow[tc + 32] = acc[r][1];
        crow[tc + 64] = acc[r][2];
        crow[tc + 96] = acc[r][3];
    }
}

// ---------------------------------------------------------------------------
// Sinkhorn column-sum pass. One wave per row (lane holds k = lane*4..+3).
// FIRST: cs[k] += sum_b E[b,k]           (beta0 == 1, global scale cancels)
// else : per row s = sum_k alpha[k]E[b,k]; beta = 1/(B*s); cs[k] += E[b,k]*beta
// ---------------------------------------------------------------------------
template<bool FIRST>
__global__ __launch_bounds__(256) void pass_colsum(
    const float* __restrict__ code,
    const float* __restrict__ alpha,
    float* __restrict__ cs)
{
    const int m = blockIdx.y;
    const float* cm = code + (size_t)m * BATCH * KCODE;
    const int lane = threadIdx.x & 63;
    const int gw = (blockIdx.x * blockDim.x + threadIdx.x) >> 6;
    const int nw = (gridDim.x * blockDim.x) >> 6;

    float4 av = make_float4(0.f, 0.f, 0.f, 0.f);
    if (!FIRST) av = ((const float4*)(alpha + m * KCODE))[lane];

    float acc0 = 0.f, acc1 = 0.f, acc2 = 0.f, acc3 = 0.f;
    for (int b = gw; b < BATCH; b += nw) {
        float4 c = ((const float4*)(cm + (size_t)b * KCODE))[lane];
        float4 e = exp4(c, 20.0f);
        if (FIRST) {
            acc0 += e.x; acc1 += e.y; acc2 += e.z; acc3 += e.w;
        } else {
            float s = dot4(av, e);
            #pragma unroll
            for (int off = 32; off >= 1; off >>= 1) s += __shfl_xor(s, off, 64);
            float beta = 1.0f / (16384.0f * s);
            acc0 += e.x * beta; acc1 += e.y * beta;
            acc2 += e.z * beta; acc3 += e.w * beta;
        }
    }
    __shared__ float csl[KCODE];
    csl[threadIdx.x] = 0.f;               // blockDim == 256 == KCODE
    __syncthreads();
    atomicAdd(&csl[lane*4 + 0], acc0);
    atomicAdd(&csl[lane*4 + 1], acc1);
    atomicAdd(&csl[lane*4 + 2], acc2);
    atomicAdd(&csl[lane*4 + 3], acc3);
    __syncthreads();
    atomicAdd(&cs[m * KCODE + threadIdx.x], csl[threadIdx.x]);
}

// alpha[k] = 1/(K * cs[k]); zero cs for the next pass.
__global__ void alpha_update_kernel(float* __restrict__ alpha, float* __restrict__ cs)
{
    const int i = blockIdx.x * KCODE + threadIdx.x;
    alpha[i] = 1.0f / (256.0f * cs[i]);
    cs[i] = 0.0f;
}

// ---------------------------------------------------------------------------
// Fused final pass: per row b, compute beta3 inline, q = E*alpha/sE
// (sum_k q = 1 exactly), per-matrix lse of code/g, 8 cross dots, accumulate
// loss/2 + align/6. One wave per row.
// NOTE: after the butterfly reductions every lane holds the identical
// fully-reduced row value -> only lane 0 may deposit it (the 64x bug).
// ---------------------------------------------------------------------------
__global__ __launch_bounds__(256) void ce_loss_kernel(
    const float* __restrict__ code,
    const float* __restrict__ alpha,
    const float* __restrict__ gamma_p,
    float* __restrict__ out)
{
    const int lane = threadIdx.x & 63;
    const int gw = (blockIdx.x * blockDim.x + threadIdx.x) >> 6;
    const int nw = (gridDim.x * blockDim.x) >> 6;
    const float g = fminf(fmaxf(gamma_p[0], 0.01f), 0.99f);
    const float invg = 1.0f / g;

    float4 al[5];
    #pragma unroll
    for (int m = 0; m < 5; ++m) al[m] = ((const float4*)(alpha + m * KCODE))[lane];

    float wacc = 0.f;
    for (int b = gw; b < BATCH; b += nw) {
        float4 c[5], q[5];
        float lse[5];
        #pragma unroll
        for (int m = 0; m < 5; ++m)
            c[m] = ((const float4*)(code + (size_t)m * BATCH * KCODE + (size_t)b * KCODE))[lane];
        #pragma unroll
        for (int m = 0; m < 5; ++m) {
            float4 e = exp4(c[m], 20.0f);
            float s = dot4(al[m], e);
            float4 le = exp4(c[m], invg);
            float l = le.x + le.y + le.z + le.w;
            #pragma unroll
            for (int off = 32; off >= 1; off >>= 1) {
                s += __shfl_xor(s, off, 64);
                l += __shfl_xor(l, off, 64);
            }
            float invs = 1.0f / s;        // q = E*alpha/sE  (B cancels)
            q[m] = make_float4(e.x*al[m].x*invs, e.y*al[m].y*invs,
                               e.z*al[m].z*invs, e.w*al[m].w*invs);
            lse[m] = __logf(l);
        }
        float p[8];
        p[0] = dot4(q[0], c[1]);  // d(q_user, c_id)
        p[1] = dot4(q[1], c[0]);  // d(q_id, c_user)
        p[2] = dot4(q[2], c[3]);
        p[3] = dot4(q[2], c[4]);
        p[4] = dot4(q[3], c[2]);
        p[5] = dot4(q[3], c[4]);
        p[6] = dot4(q[4], c[2]);
        p[7] = dot4(q[4], c[3]);
        #pragma unroll
        for (int off = 32; off >= 1; off >>= 1) {
            #pragma unroll
            for (int j = 0; j < 8; ++j) p[j] += __shfl_xor(p[j], off, 64);
        }
        float lossr  = lse[0] + lse[1] - invg * (p[0] + p[1]);
        float alignr = 2.f * (lse[2] + lse[3] + lse[4])
                     - invg * (p[2] + p[3] + p[4] + p[5] + p[6] + p[7]);
        wacc += lossr * 0.5f + alignr * (1.0f / 6.0f);
    }
    // wacc is identical on all 64 lanes (everything above is fully wave-reduced);
    // deposit ONCE per wave — do NOT butterfly-sum the 64 identical copies.
    __shared__ float bl[4];
    if (lane == 0) bl[threadIdx.x >> 6] = wacc;
    __syncthreads();
    if (threadIdx.x == 0) {
        float t = bl[0] + bl[1] + bl[2] + bl[3];
        atomicAdd(out, t * (1.0f / 16384.0f));
    }
}

// ---------------------------------------------------------------------------
extern "C" void kernel_launch(void* const* d_in, const int* in_sizes, int n_in,
                              void* d_out, int out_size, void* d_ws, size_t ws_size,
                              hipStream_t stream)
{
    const float* user_emb = (const float*)d_in[0];
    const float* id_emb   = (const float*)d_in[1];
    const float* img_emb  = (const float*)d_in[2];
    const float* txt_emb  = (const float*)d_in[3];
    const int*   users    = (const int*)d_in[4];
    const int*   items    = (const int*)d_in[5];
    const float* w_feat   = (const float*)d_in[6];
    const float* w_ii     = (const float*)d_in[7];
    const float* gamma    = (const float*)d_in[8];
    float* out = (float*)d_out;

    // workspace layout: 5 code matrices (80 MB) + alpha[5][256] + cs[5][256]
    float* code  = (float*)d_ws;
    float* alpha = code + (size_t)NMAT * BATCH * KCODE;
    float* cs    = alpha + NMAT * KCODE;

    hipMemsetAsync(out, 0, sizeof(float), stream);
    hipMemsetAsync(cs, 0, NMAT * KCODE * sizeof(float), stream);

    gemm_code_kernel<<<dim3(BATCH/64, 2, NMAT), 256, 0, stream>>>(
        user_emb, id_emb, img_emb, txt_emb, users, items, w_feat, w_ii, code);

    pass_colsum<true ><<<dim3(64, NMAT), 256, 0, stream>>>(code, alpha, cs);
    alpha_update_kernel<<<NMAT, KCODE, 0, stream>>>(alpha, cs);
    pass_colsum<false><<<dim3(64, NMAT), 256, 0, stream>>>(code, alpha, cs);
    alpha_update_kernel<<<NMAT, KCODE, 0, stream>>>(alpha, cs);
    pass_colsum<false><<<dim3(64, NMAT), 256, 0, stream>>>(code, alpha, cs);
    alpha_update_kernel<<<NMAT, KCODE, 0, stream>>>(alpha, cs);

    ce_loss_kernel<<<256, 256, 0, stream>>>(code, alpha, gamma, out);
}

// Round 3
// 149.669 us; speedup vs baseline: 1.4040x; 1.4040x over previous
//
#include <hip/hip_runtime.h>
#include <hip/hip_bf16.h>
#include <math.h>

#define BATCH 16384
#define DIM   64
#define KCODE 256
#define NMAT  5

static __device__ __forceinline__ float dot4(float4 a, float4 b) {
    return a.x*b.x + a.y*b.y + a.z*b.z + a.w*b.w;
}
static __device__ __forceinline__ float sum4(float4 a) { return a.x+a.y+a.z+a.w; }
static __device__ __forceinline__ float ss4(float4 a) { return dot4(a, a); }
static __device__ __forceinline__ float4 exp4(float4 v, float s) {
    return make_float4(__expf(v.x*s), __expf(v.y*s), __expf(v.z*s), __expf(v.w*s));
}
static __device__ __forceinline__ float4 mul44(float4 a, float4 b) {
    return make_float4(a.x*b.x, a.y*b.y, a.z*b.z, a.w*b.w);
}
static __device__ __forceinline__ float4 add44(float4 a, float4 b) {
    return make_float4(a.x+b.x, a.y+b.y, a.z+b.z, a.w+b.w);
}

// ---------------------------------------------------------------------------
// Kernel 1: fused gather + l2norm(A) + l2norm(W) + SGEMM + Sinkhorn colsum #1.
// C[m][b][k] = <A_m[b,:], W_m[k,:]>; epilogue accumulates cs1[k] += sum_b e^{20c}.
// Block tile 64x128, 256 threads, 8x4 per thread. LDS ~51K -> 3 blocks/CU.
// ---------------------------------------------------------------------------
__global__ __launch_bounds__(256) void gemm_code_cs1_kernel(
    const float* __restrict__ user_emb,
    const float* __restrict__ id_emb,
    const float* __restrict__ image_emb,
    const float* __restrict__ text_emb,
    const int*  __restrict__ users,
    const int*  __restrict__ items,
    const float* __restrict__ w_feat,
    const float* __restrict__ w_ii,
    float* __restrict__ code,
    float* __restrict__ cs1)
{
    const int m  = blockIdx.z;
    const int r0 = blockIdx.x * 64;
    const int kh = blockIdx.y;            // 0/1 -> k offset kh*128

    const float* src; const int* idxv; const float* w;
    switch (m) {
        case 0:  src = user_emb;  idxv = users; w = w_feat; break;
        case 1:  src = id_emb;    idxv = items; w = w_feat; break;
        case 2:  src = id_emb;    idxv = items; w = w_ii;   break;
        case 3:  src = image_emb; idxv = items; w = w_ii;   break;
        default: src = text_emb;  idxv = items; w = w_ii;   break;
    }

    __shared__ float As[64][64];     // [d][row]
    __shared__ float Ws[64][128];    // [d][klocal]
    __shared__ float redA[4][64];
    __shared__ float redW[2][128];
    __shared__ float csl[128];

    const int tid = threadIdx.x;

    // ---- load A rows (gather): thread t -> row (t&63), d-segment (t>>6)*16 ----
    const int ar   = tid & 63;
    const int aseg = tid >> 6;
    const int gidx = idxv[r0 + ar];
    const float4* ap = (const float4*)(src + (size_t)gidx * DIM + aseg * 16);
    float4 a0 = ap[0], a1 = ap[1], a2 = ap[2], a3 = ap[3];
    redA[aseg][ar] = ss4(a0) + ss4(a1) + ss4(a2) + ss4(a3);

    // ---- load W rows: thread t -> local k (t&127), d-half (t>>7)*32 ----
    const int wr = tid & 127;
    const int wh = tid >> 7;
    const float4* wp = (const float4*)(w + (size_t)(kh*128 + wr) * DIM + wh * 32);
    float4 w0 = wp[0], w1 = wp[1], w2 = wp[2], w3 = wp[3];
    float4 w4 = wp[4], w5 = wp[5], w6 = wp[6], w7 = wp[7];
    redW[wh][wr] = ss4(w0)+ss4(w1)+ss4(w2)+ss4(w3)+ss4(w4)+ss4(w5)+ss4(w6)+ss4(w7);

    __syncthreads();

    {   // normalize + write A transposed
        float tot = redA[0][ar] + redA[1][ar] + redA[2][ar] + redA[3][ar];
        float inv = 1.0f / fmaxf(sqrtf(tot), 1e-12f);
        float av[16] = {a0.x,a0.y,a0.z,a0.w, a1.x,a1.y,a1.z,a1.w,
                        a2.x,a2.y,a2.z,a2.w, a3.x,a3.y,a3.z,a3.w};
        const int db = aseg * 16;
        #pragma unroll
        for (int j = 0; j < 16; ++j) As[db + j][ar] = av[j] * inv;
    }
    {   // normalize + write W transposed
        float tot = redW[0][wr] + redW[1][wr];
        float inv = 1.0f / fmaxf(sqrtf(tot), 1e-12f);
        float wv[32] = {w0.x,w0.y,w0.z,w0.w, w1.x,w1.y,w1.z,w1.w,
                        w2.x,w2.y,w2.z,w2.w, w3.x,w3.y,w3.z,w3.w,
                        w4.x,w4.y,w4.z,w4.w, w5.x,w5.y,w5.z,w5.w,
                        w6.x,w6.y,w6.z,w6.w, w7.x,w7.y,w7.z,w7.w};
        const int db = wh * 32;
        #pragma unroll
        for (int j = 0; j < 32; ++j) Ws[db + j][wr] = wv[j] * inv;
    }
    if (tid < 128) csl[tid] = 0.0f;
    __syncthreads();

    // ---- compute ----
    const int tr = tid >> 5;
    const int tc = tid & 31;
    float acc[8][4];
    #pragma unroll
    for (int r = 0; r < 8; ++r)
        #pragma unroll
        for (int c = 0; c < 4; ++c) acc[r][c] = 0.0f;

    #pragma unroll 16
    for (int d = 0; d < 64; ++d) {
        float4 av0 = *(const float4*)&As[d][tr*8];
        float4 av1 = *(const float4*)&As[d][tr*8 + 4];
        float ar8[8] = {av0.x,av0.y,av0.z,av0.w, av1.x,av1.y,av1.z,av1.w};
        float wc[4]  = {Ws[d][tc], Ws[d][tc+32], Ws[d][tc+64], Ws[d][tc+96]};
        #pragma unroll
        for (int r = 0; r < 8; ++r)
            #pragma unroll
            for (int c = 0; c < 4; ++c)
                acc[r][c] = fmaf(ar8[r], wc[c], acc[r][c]);
    }

    // ---- store C ----
    float* cbase = code + (size_t)m * BATCH * KCODE + (size_t)r0 * KCODE + kh * 128;
    #pragma unroll
    for (int r = 0; r < 8; ++r) {
        float* crow = cbase + (size_t)(tr*8 + r) * KCODE;
        crow[tc]      = acc[r][0];
        crow[tc + 32] = acc[r][1];
        crow[tc + 64] = acc[r][2];
        crow[tc + 96] = acc[r][3];
    }

    // ---- fused Sinkhorn colsum #1: cs1[k] += sum_rows exp(20*c) ----
    float es[4] = {0.f, 0.f, 0.f, 0.f};
    #pragma unroll
    for (int r = 0; r < 8; ++r)
        #pragma unroll
        for (int c = 0; c < 4; ++c) es[c] += __expf(20.0f * acc[r][c]);
    #pragma unroll
    for (int c = 0; c < 4; ++c) atomicAdd(&csl[tc + 32*c], es[c]);
    __syncthreads();
    if (tid < 128) atomicAdd(&cs1[m * KCODE + kh*128 + tid], csl[tid]);
}

// ---------------------------------------------------------------------------
// Sinkhorn column-sum pass (iterations 2,3). alpha computed inline from
// cs_prev: alpha[k] = 1/(K*cs_prev[k]). One wave per row-slice, lane = 4 k's.
// per row: s = sum_k alpha*E; beta = 1/(B*s); cs_next[k] += E*beta.
// ---------------------------------------------------------------------------
__global__ __launch_bounds__(256) void pass_colsum(
    const float* __restrict__ code,
    const float* __restrict__ cs_prev,
    float* __restrict__ cs_next)
{
    const int m = blockIdx.y;
    const float* cm = code + (size_t)m * BATCH * KCODE;
    const int lane = threadIdx.x & 63;
    const int gw = (blockIdx.x * blockDim.x + threadIdx.x) >> 6;
    const int nw = (gridDim.x * blockDim.x) >> 6;

    float4 csv = ((const float4*)(cs_prev + m * KCODE))[lane];
    const float4 av = make_float4(
        __builtin_amdgcn_rcpf(256.0f * csv.x),
        __builtin_amdgcn_rcpf(256.0f * csv.y),
        __builtin_amdgcn_rcpf(256.0f * csv.z),
        __builtin_amdgcn_rcpf(256.0f * csv.w));

    float acc0 = 0.f, acc1 = 0.f, acc2 = 0.f, acc3 = 0.f;
    for (int b = gw; b < BATCH; b += nw) {
        float4 c = ((const float4*)(cm + (size_t)b * KCODE))[lane];
        float4 e = exp4(c, 20.0f);
        float s = dot4(av, e);
        #pragma unroll
        for (int off = 32; off >= 1; off >>= 1) s += __shfl_xor(s, off, 64);
        float beta = __builtin_amdgcn_rcpf(16384.0f * s);
        acc0 = fmaf(e.x, beta, acc0); acc1 = fmaf(e.y, beta, acc1);
        acc2 = fmaf(e.z, beta, acc2); acc3 = fmaf(e.w, beta, acc3);
    }
    __shared__ float csl[KCODE];
    csl[threadIdx.x] = 0.f;               // blockDim == 256 == KCODE
    __syncthreads();
    atomicAdd(&csl[lane*4 + 0], acc0);
    atomicAdd(&csl[lane*4 + 1], acc1);
    atomicAdd(&csl[lane*4 + 2], acc2);
    atomicAdd(&csl[lane*4 + 3], acc3);
    __syncthreads();
    atomicAdd(&cs_next[m * KCODE + threadIdx.x], csl[threadIdx.x]);
}

// ---------------------------------------------------------------------------
// Fused CE pass: alpha3 inline from cs3; per row, reduce s_m and l_m (10
// butterflies); the 8 q.c dots are folded into ONE per-lane partial that is
// reduced once per wave at loop exit. lse part accumulated (identical on all
// lanes), deposited once per wave.
// ---------------------------------------------------------------------------
__global__ __launch_bounds__(256) void ce_loss_kernel(
    const float* __restrict__ code,
    const float* __restrict__ cs3,
    const float* __restrict__ gamma_p,
    float* __restrict__ out)
{
    const int lane = threadIdx.x & 63;
    const int gw = (blockIdx.x * blockDim.x + threadIdx.x) >> 6;
    const int nw = (gridDim.x * blockDim.x) >> 6;
    const float g = fminf(fmaxf(gamma_p[0], 0.01f), 0.99f);
    const float invg = 1.0f / g;

    float4 al[5];
    #pragma unroll
    for (int m = 0; m < 5; ++m) {
        float4 csv = ((const float4*)(cs3 + m * KCODE))[lane];
        al[m] = make_float4(
            __builtin_amdgcn_rcpf(256.0f * csv.x),
            __builtin_amdgcn_rcpf(256.0f * csv.y),
            __builtin_amdgcn_rcpf(256.0f * csv.z),
            __builtin_amdgcn_rcpf(256.0f * csv.w));
    }

    float vacc = 0.f;      // lane-partial of the weighted q.c dots
    float waccL = 0.f;     // lse part (identical across lanes)
    for (int b = gw; b < BATCH; b += nw) {
        float4 c[5], f[5];
        float invs[5], lg[5];
        #pragma unroll
        for (int m = 0; m < 5; ++m)
            c[m] = ((const float4*)(code + (size_t)m * BATCH * KCODE + (size_t)b * KCODE))[lane];
        #pragma unroll
        for (int m = 0; m < 5; ++m) {
            float4 e = exp4(c[m], 20.0f);
            f[m] = mul44(e, al[m]);               // alpha * E
            float s = sum4(f[m]);
            float4 le = exp4(c[m], invg);
            float l = sum4(le);
            #pragma unroll
            for (int off = 32; off >= 1; off >>= 1) {
                s += __shfl_xor(s, off, 64);
                l += __shfl_xor(l, off, 64);
            }
            invs[m] = __builtin_amdgcn_rcpf(s);   // q = f / s
            lg[m] = __logf(l);
        }
        float4 c34 = add44(c[3], c[4]);
        float4 c24 = add44(c[2], c[4]);
        float4 c23 = add44(c[2], c[3]);
        float u = 0.5f * (dot4(f[0], c[1]) * invs[0] + dot4(f[1], c[0]) * invs[1])
                + (1.0f/6.0f) * (dot4(f[2], c34) * invs[2]
                               + dot4(f[3], c24) * invs[3]
                               + dot4(f[4], c23) * invs[4]);
        vacc += u;
        waccL += 0.5f * (lg[0] + lg[1]) + (1.0f/3.0f) * (lg[2] + lg[3] + lg[4]);
    }
    #pragma unroll
    for (int off = 32; off >= 1; off >>= 1) vacc += __shfl_xor(vacc, off, 64);
    float t = waccL - invg * vacc;   // per-wave total (same on all lanes)

    __shared__ float bl[4];
    if (lane == 0) bl[threadIdx.x >> 6] = t;
    __syncthreads();
    if (threadIdx.x == 0) {
        float tt = bl[0] + bl[1] + bl[2] + bl[3];
        atomicAdd(out, tt * (1.0f / 16384.0f));
    }
}

// ---------------------------------------------------------------------------
extern "C" void kernel_launch(void* const* d_in, const int* in_sizes, int n_in,
                              void* d_out, int out_size, void* d_ws, size_t ws_size,
                              hipStream_t stream)
{
    const float* user_emb = (const float*)d_in[0];
    const float* id_emb   = (const float*)d_in[1];
    const float* img_emb  = (const float*)d_in[2];
    const float* txt_emb  = (const float*)d_in[3];
    const int*   users    = (const int*)d_in[4];
    const int*   items    = (const int*)d_in[5];
    const float* w_feat   = (const float*)d_in[6];
    const float* w_ii     = (const float*)d_in[7];
    const float* gamma    = (const float*)d_in[8];
    float* out = (float*)d_out;

    // ws layout: code[5][16384][256] (80 MB) + cs1/cs2/cs3 [5][256] each
    float* code = (float*)d_ws;
    float* cs1  = code + (size_t)NMAT * BATCH * KCODE;
    float* cs2  = cs1 + NMAT * KCODE;
    float* cs3  = cs2 + NMAT * KCODE;

    hipMemsetAsync(out, 0, sizeof(float), stream);
    hipMemsetAsync(cs1, 0, 3 * NMAT * KCODE * sizeof(float), stream);

    gemm_code_cs1_kernel<<<dim3(BATCH/64, 2, NMAT), 256, 0, stream>>>(
        user_emb, id_emb, img_emb, txt_emb, users, items, w_feat, w_ii, code, cs1);

    pass_colsum<<<dim3(256, NMAT), 256, 0, stream>>>(code, cs1, cs2);
    pass_colsum<<<dim3(256, NMAT), 256, 0, stream>>>(code, cs2, cs3);

    ce_loss_kernel<<<1024, 256, 0, stream>>>(code, cs3, gamma, out);
}

// Round 4
// 146.690 us; speedup vs baseline: 1.4325x; 1.0203x over previous
//
#include <hip/hip_runtime.h>
#include <hip/hip_bf16.h>
#include <math.h>

#define BATCH 16384
#define DIM   64
#define KCODE 256

typedef unsigned short ushort_t;
typedef __attribute__((ext_vector_type(8))) short bf16x8;   // 8 bf16 (4 VGPR)
typedef __attribute__((ext_vector_type(4))) float f32x4;

#define MFMA16 __builtin_amdgcn_mfma_f32_16x16x32_bf16

static __device__ __forceinline__ float ss4(float4 a) {
    return a.x*a.x + a.y*a.y + a.z*a.z + a.w*a.w;
}
static __device__ __forceinline__ short f2bs(float f) {   // f32 -> bf16 RNE
    unsigned u = __float_as_uint(f);
    u += 0x7FFFu + ((u >> 16) & 1u);
    return (short)(u >> 16);
}
static __device__ __forceinline__ bf16x8 pack8(float4 a, float4 b, float s) {
    bf16x8 r;
    r[0]=f2bs(a.x*s); r[1]=f2bs(a.y*s); r[2]=f2bs(a.z*s); r[3]=f2bs(a.w*s);
    r[4]=f2bs(b.x*s); r[5]=f2bs(b.y*s); r[6]=f2bs(b.z*s); r[7]=f2bs(b.w*s);
    return r;
}

// ---------------------------------------------------------------------------
// K1: gather + l2norm(A) -> bf16 A_norm; l2norm(W) -> bf16 W_norm; MFMA GEMM
// of this block's 64 rows; Sinkhorn colsum #1 (cs1[k] += sum_b exp(20c)).
// grid (256, 5): x = 64-row block, y = matrix. LDS: W 32K frag-linear + A 8K.
// ---------------------------------------------------------------------------
__global__ __launch_bounds__(256) void k1_prep_gemm_cs1(
    const float* __restrict__ ue, const float* __restrict__ ie,
    const float* __restrict__ me, const float* __restrict__ te,
    const int* __restrict__ users, const int* __restrict__ items,
    const float* __restrict__ wfeat, const float* __restrict__ wii,
    ushort_t* __restrict__ An, ushort_t* __restrict__ Wn,
    float* __restrict__ cs1)
{
    const int m  = blockIdx.y;
    const int bx = blockIdx.x;
    const int t  = threadIdx.x;
    const int aset = (m==0) ? 0 : (m<3) ? 1 : (m==3) ? 2 : 3;
    const int wset = (m<2) ? 0 : 1;
    const float* asrc = (aset==0)?ue:(aset==1)?ie:(aset==2)?me:te;
    const int*  idxv = (m==0)?users:items;
    const float* wsrc = (wset==0)?wfeat:wii;
    const bool store_w = ((m==0 || m==2) && bx==0);
    const bool store_a = (m != 2);     // m=1 already stores set 1

    __shared__ short Wl[16384];   // 2048 fragment chunks * 8 bf16 (32 KB)
    __shared__ short Al[4096];    // 512 chunks (8 KB)
    __shared__ float redA[4][64];
    __shared__ float csl[256];

    // ---- W: thread t owns W row t: load f32, normalize, pack to frag-linear LDS
    {
        const float4* wp = (const float4*)(wsrc + t*DIM);
        float4 q[16]; float ss = 0.f;
        #pragma unroll
        for (int i=0;i<16;++i){ q[i]=wp[i]; ss += ss4(q[i]); }
        const float inv = 1.0f / fmaxf(sqrtf(ss), 1e-12f);
        const int kt = t>>4, lr = t&15;
        #pragma unroll
        for (int kk=0;kk<2;++kk)
            #pragma unroll
            for (int fs=0;fs<4;++fs){
                const int qi = kk*8 + fs*2;
                bf16x8 pk = pack8(q[qi], q[qi+1], inv);
                const int cid = (kt*2+kk)*64 + fs*16 + lr;
                *(bf16x8*)&Wl[cid*8] = pk;
                if (store_w)
                    *(bf16x8*)(Wn + ((size_t)wset*KCODE + t)*DIM + kk*32 + fs*8) = pk;
            }
    }

    // ---- A: thread t -> row rb = t&63 of this block, d-segment seg = t>>6
    const int rb = t&63, seg = t>>6;
    const int gidx = idxv[bx*64 + rb];
    const float4* ap = (const float4*)(asrc + (size_t)gidx*DIM + seg*16);
    float4 a0=ap[0], a1=ap[1], a2=ap[2], a3=ap[3];
    redA[seg][rb] = ss4(a0)+ss4(a1)+ss4(a2)+ss4(a3);
    csl[t] = 0.f;
    __syncthreads();

    {
        const float tot = redA[0][rb]+redA[1][rb]+redA[2][rb]+redA[3][rb];
        const float inv = 1.0f/fmaxf(sqrtf(tot),1e-12f);
        bf16x8 c0 = pack8(a0, a1, inv);       // d = seg*16 .. +7
        bf16x8 c1 = pack8(a2, a3, inv);       // d = seg*16+8 .. +15
        const int kk = seg>>1, fs0 = (seg&1)*2;
        const int base = ((rb>>4)*2 + kk)*64;
        *(bf16x8*)&Al[(base + fs0*16     + (rb&15))*8] = c0;
        *(bf16x8*)&Al[(base + (fs0+1)*16 + (rb&15))*8] = c1;
        if (store_a) {
            ushort_t* dst = An + ((size_t)aset*BATCH + bx*64 + rb)*DIM + seg*16;
            *(bf16x8*)dst       = c0;
            *(bf16x8*)(dst + 8) = c1;
        }
    }
    __syncthreads();

    // ---- GEMM: wave w owns 16-row tile w; cs1 colsum of exp(20c) ----
    const int w = t>>6, lane = t&63;
    bf16x8 af0 = *(bf16x8*)&Al[((w*2+0)*64 + lane)*8];
    bf16x8 af1 = *(bf16x8*)&Al[((w*2+1)*64 + lane)*8];
    #pragma unroll 4
    for (int kt=0; kt<16; ++kt){
        bf16x8 wf0 = *(bf16x8*)&Wl[((kt*2+0)*64 + lane)*8];
        bf16x8 wf1 = *(bf16x8*)&Wl[((kt*2+1)*64 + lane)*8];
        f32x4 acc = {0.f,0.f,0.f,0.f};
        acc = MFMA16(af0, wf0, acc, 0,0,0);
        acc = MFMA16(af1, wf1, acc, 0,0,0);
        float es = __expf(20.f*acc[0]) + __expf(20.f*acc[1])
                 + __expf(20.f*acc[2]) + __expf(20.f*acc[3]);
        atomicAdd(&csl[kt*16 + (lane&15)], es);
    }
    __syncthreads();
    atomicAdd(&cs1[m*KCODE + t], csl[t]);
}

// ---------------------------------------------------------------------------
// K2/K3: Sinkhorn pass p>=2. Recompute c via MFMA; alpha inline from cs_prev;
// per-row s = sum alpha*E (4-shfl butterfly); beta = 1/(B*s);
// cs_next[k] += sum_b E*beta.  grid (128, 5).
// ---------------------------------------------------------------------------
__global__ __launch_bounds__(256) void k_pass(
    const ushort_t* __restrict__ An, const ushort_t* __restrict__ Wn,
    const float* __restrict__ cs_prev, float* __restrict__ cs_next)
{
    const int m = blockIdx.y;
    const int aset = (m==0)?0:(m<3)?1:(m==3)?2:3;
    const int wset = (m<2)?0:1;
    const int t = threadIdx.x, lane = t&63, w = t>>6;

    __shared__ short Wl[16384];
    __shared__ float csl[256];

    #pragma unroll
    for (int c8=0;c8<8;++c8){
        const int cid = c8*256 + t;
        const int kt = cid>>7, kk=(cid>>6)&1, ln=cid&63;
        const ushort_t* src = Wn + ((size_t)wset*KCODE + kt*16 + (ln&15))*DIM
                                 + kk*32 + (ln>>4)*8;
        *(bf16x8*)&Wl[cid*8] = *(const bf16x8*)src;
    }
    csl[t] = 0.f;
    float ar[16];
    #pragma unroll
    for (int kt=0;kt<16;++kt)
        ar[kt] = __builtin_amdgcn_rcpf(256.0f * cs_prev[m*KCODE + kt*16 + (lane&15)]);
    __syncthreads();

    float csp[16];
    #pragma unroll
    for (int kt=0;kt<16;++kt) csp[kt]=0.f;

    for (int rt = blockIdx.x*4 + w; rt < BATCH/16; rt += gridDim.x*4){
        const int r0 = rt*16;
        const ushort_t* ab = An + ((size_t)aset*BATCH + r0 + (lane&15))*DIM + (lane>>4)*8;
        bf16x8 af0 = *(const bf16x8*)ab;
        bf16x8 af1 = *(const bf16x8*)(ab + 32);
        float ev[16][4];
        float sp0=0.f, sp1=0.f, sp2=0.f, sp3=0.f;
        #pragma unroll
        for (int kt=0;kt<16;++kt){
            bf16x8 wf0 = *(bf16x8*)&Wl[((kt*2+0)*64+lane)*8];
            bf16x8 wf1 = *(bf16x8*)&Wl[((kt*2+1)*64+lane)*8];
            f32x4 acc = {0.f,0.f,0.f,0.f};
            acc = MFMA16(af0, wf0, acc, 0,0,0);
            acc = MFMA16(af1, wf1, acc, 0,0,0);
            ev[kt][0]=__expf(20.f*acc[0]); ev[kt][1]=__expf(20.f*acc[1]);
            ev[kt][2]=__expf(20.f*acc[2]); ev[kt][3]=__expf(20.f*acc[3]);
            sp0 = fmaf(ar[kt], ev[kt][0], sp0);
            sp1 = fmaf(ar[kt], ev[kt][1], sp1);
            sp2 = fmaf(ar[kt], ev[kt][2], sp2);
            sp3 = fmaf(ar[kt], ev[kt][3], sp3);
        }
        #pragma unroll
        for (int off=8; off>=1; off>>=1){
            sp0 += __shfl_xor(sp0, off, 64);
            sp1 += __shfl_xor(sp1, off, 64);
            sp2 += __shfl_xor(sp2, off, 64);
            sp3 += __shfl_xor(sp3, off, 64);
        }
        const float b0 = __builtin_amdgcn_rcpf(16384.f*sp0);
        const float b1 = __builtin_amdgcn_rcpf(16384.f*sp1);
        const float b2 = __builtin_amdgcn_rcpf(16384.f*sp2);
        const float b3 = __builtin_amdgcn_rcpf(16384.f*sp3);
        #pragma unroll
        for (int kt=0;kt<16;++kt)
            csp[kt] += ev[kt][0]*b0 + ev[kt][1]*b1 + ev[kt][2]*b2 + ev[kt][3]*b3;
    }
    #pragma unroll
    for (int kt=0;kt<16;++kt)
        atomicAdd(&csl[kt*16 + (lane&15)], csp[kt]);
    __syncthreads();
    atomicAdd(&cs_next[m*KCODE + t], csl[t]);
}

// ---------------------------------------------------------------------------
// K4: CE. Recompute all 5 c-tiles per kt; accumulate per-lane partials of
// s_m (alpha*E), l_m (exp(c/g)), dp_m (alpha*E*cc_m); one butterfly set per
// 16-row tile; loss deposited once per wave.  grid (256).
// ---------------------------------------------------------------------------
__global__ __launch_bounds__(256) void k_ce(
    const ushort_t* __restrict__ An, const ushort_t* __restrict__ Wn,
    const float* __restrict__ cs3, const float* __restrict__ gamma_p,
    float* __restrict__ out)
{
    const int t = threadIdx.x, lane = t&63, w = t>>6;
    __shared__ short Wl[32768];   // both wsets, 64 KB
    __shared__ float al[1280];

    #pragma unroll
    for (int c16=0;c16<16;++c16){
        const int cid = c16*256 + t;
        const int ws = cid>>11, rem = cid&2047;
        const int kt = rem>>7, kk=(rem>>6)&1, ln=rem&63;
        const ushort_t* src = Wn + ((size_t)ws*KCODE + kt*16 + (ln&15))*DIM
                                 + kk*32 + (ln>>4)*8;
        *(bf16x8*)&Wl[cid*8] = *(const bf16x8*)src;
    }
    #pragma unroll
    for (int mm=0;mm<5;++mm)
        al[mm*256+t] = __builtin_amdgcn_rcpf(256.0f * cs3[mm*KCODE + t]);
    const float g = fminf(fmaxf(gamma_p[0], 0.01f), 0.99f);
    const float invg = 1.0f/g;
    __syncthreads();

    float wacc = 0.f;
    for (int rt = blockIdx.x*4 + w; rt < BATCH/16; rt += gridDim.x*4){
        const int r0 = rt*16;
        bf16x8 af[4][2];
        #pragma unroll
        for (int s=0;s<4;++s){
            const ushort_t* ab = An + ((size_t)s*BATCH + r0 + (lane&15))*DIM + (lane>>4)*8;
            af[s][0] = *(const bf16x8*)ab;
            af[s][1] = *(const bf16x8*)(ab + 32);
        }
        float S[5][4], L[5][4], DP[5][4];
        #pragma unroll
        for (int mm=0;mm<5;++mm)
            #pragma unroll
            for (int r=0;r<4;++r){ S[mm][r]=0.f; L[mm][r]=0.f; DP[mm][r]=0.f; }

        #pragma unroll 2
        for (int kt=0;kt<16;++kt){
            bf16x8 wf[2][2];
            #pragma unroll
            for (int ws=0;ws<2;++ws){
                wf[ws][0] = *(bf16x8*)&Wl[((ws*2048) + (kt*2+0)*64 + lane)*8];
                wf[ws][1] = *(bf16x8*)&Wl[((ws*2048) + (kt*2+1)*64 + lane)*8];
            }
            const f32x4 Z = {0.f,0.f,0.f,0.f};
            f32x4 c[5];
            c[0] = MFMA16(af[0][0], wf[0][0], Z, 0,0,0);
            c[0] = MFMA16(af[0][1], wf[0][1], c[0], 0,0,0);
            c[1] = MFMA16(af[1][0], wf[0][0], Z, 0,0,0);
            c[1] = MFMA16(af[1][1], wf[0][1], c[1], 0,0,0);
            c[2] = MFMA16(af[1][0], wf[1][0], Z, 0,0,0);
            c[2] = MFMA16(af[1][1], wf[1][1], c[2], 0,0,0);
            c[3] = MFMA16(af[2][0], wf[1][0], Z, 0,0,0);
            c[3] = MFMA16(af[2][1], wf[1][1], c[3], 0,0,0);
            c[4] = MFMA16(af[3][0], wf[1][0], Z, 0,0,0);
            c[4] = MFMA16(af[3][1], wf[1][1], c[4], 0,0,0);

            float am[5];
            #pragma unroll
            for (int mm=0;mm<5;++mm) am[mm] = al[mm*256 + kt*16 + (lane&15)];

            float fm[5][4];
            #pragma unroll
            for (int mm=0;mm<5;++mm)
                #pragma unroll
                for (int r=0;r<4;++r){
                    const float cv = c[mm][r];
                    const float f = am[mm] * __expf(20.f*cv);
                    fm[mm][r] = f;
                    S[mm][r] += f;
                    L[mm][r] += __expf(invg*cv);
                }
            #pragma unroll
            for (int r=0;r<4;++r){
                DP[0][r] = fmaf(fm[0][r], c[1][r], DP[0][r]);
                DP[1][r] = fmaf(fm[1][r], c[0][r], DP[1][r]);
                const float c34 = c[3][r]+c[4][r];
                const float c24 = c[2][r]+c[4][r];
                const float c23 = c[2][r]+c[3][r];
                DP[2][r] = fmaf(fm[2][r], c34, DP[2][r]);
                DP[3][r] = fmaf(fm[3][r], c24, DP[3][r]);
                DP[4][r] = fmaf(fm[4][r], c23, DP[4][r]);
            }
        }
        #pragma unroll
        for (int off=8; off>=1; off>>=1)
            #pragma unroll
            for (int mm=0;mm<5;++mm)
                #pragma unroll
                for (int r=0;r<4;++r){
                    S[mm][r]  += __shfl_xor(S[mm][r],  off, 64);
                    L[mm][r]  += __shfl_xor(L[mm][r],  off, 64);
                    DP[mm][r] += __shfl_xor(DP[mm][r], off, 64);
                }
        #pragma unroll
        for (int r=0;r<4;++r){
            const float u =
                0.5f*(DP[0][r]*__builtin_amdgcn_rcpf(S[0][r])
                    + DP[1][r]*__builtin_amdgcn_rcpf(S[1][r]))
              + (1.f/6.f)*(DP[2][r]*__builtin_amdgcn_rcpf(S[2][r])
                         + DP[3][r]*__builtin_amdgcn_rcpf(S[3][r])
                         + DP[4][r]*__builtin_amdgcn_rcpf(S[4][r]));
            const float Lr =
                0.5f*(__logf(L[0][r]) + __logf(L[1][r]))
              + (1.f/3.f)*(__logf(L[2][r]) + __logf(L[3][r]) + __logf(L[4][r]));
            wacc += Lr - invg*u;
        }
    }
    wacc += __shfl_xor(wacc, 16, 64);
    wacc += __shfl_xor(wacc, 32, 64);
    if (lane == 0) atomicAdd(out, wacc * (1.0f/16384.0f));
}

// ---------------------------------------------------------------------------
extern "C" void kernel_launch(void* const* d_in, const int* in_sizes, int n_in,
                              void* d_out, int out_size, void* d_ws, size_t ws_size,
                              hipStream_t stream)
{
    const float* ue    = (const float*)d_in[0];
    const float* ie    = (const float*)d_in[1];
    const float* me    = (const float*)d_in[2];
    const float* te    = (const float*)d_in[3];
    const int*   users = (const int*)d_in[4];
    const int*   items = (const int*)d_in[5];
    const float* wfeat = (const float*)d_in[6];
    const float* wii   = (const float*)d_in[7];
    const float* gamma = (const float*)d_in[8];
    float* out = (float*)d_out;

    // ws: A_norm bf16 [4][16384][64] (8 MB) | W_norm bf16 [2][256][64] | cs[3][5][256] f32
    ushort_t* An = (ushort_t*)d_ws;
    ushort_t* Wn = An + (size_t)4*BATCH*DIM;
    float* cs  = (float*)(Wn + 2*KCODE*DIM);
    float* cs1 = cs;
    float* cs2 = cs + 1280;
    float* cs3 = cs + 2560;

    hipMemsetAsync(out, 0, sizeof(float), stream);
    hipMemsetAsync(cs, 0, 3*1280*sizeof(float), stream);

    k1_prep_gemm_cs1<<<dim3(256,5), 256, 0, stream>>>(
        ue, ie, me, te, users, items, wfeat, wii, An, Wn, cs1);
    k_pass<<<dim3(128,5), 256, 0, stream>>>(An, Wn, cs1, cs2);
    k_pass<<<dim3(128,5), 256, 0, stream>>>(An, Wn, cs2, cs3);
    k_ce<<<256, 256, 0, stream>>>(An, Wn, cs3, gamma, out);
}